// Round 14
// baseline (599.006 us; speedup 1.0000x reference)
//
#include <hip/hip_runtime.h>
#include <hip/hip_bf16.h>

#define B_ 4
#define H_ 16
#define L_ 2048
#define D_ 128
#define BH_ 64

typedef __attribute__((ext_vector_type(8))) _Float16 f16x8;
typedef __attribute__((ext_vector_type(4))) float f32x4;
typedef __attribute__((ext_vector_type(16))) float f32x16;
typedef __attribute__((ext_vector_type(2))) unsigned u32x2;

#define L2E 1.44269504088896f

// gm = L2E*gelu(v) + negm. erf via A&S 7.1.27 (|eps|<=5e-4): one rcp, no exp2.
__device__ __forceinline__ float gelu_m(float v, float negm) {
  float x  = __builtin_fabsf(v) * 0.70710678118f;
  float s  = __builtin_fmaf(x,
               __builtin_fmaf(x,
                 __builtin_fmaf(x,
                   __builtin_fmaf(x, 0.078108f, 0.000972f),
                 0.230389f),
               0.278393f),
             1.0f);
  float s2 = s * s;
  float s4 = s2 * s2;
  float erfa = 1.0f - __builtin_amdgcn_rcpf(s4);   // erf(|v|/sqrt2) in [0,1)
  float erfv = copysignf(erfa, v);
  float hv   = 0.72134752f * v;                    // 0.5*L2E*v
  return __builtin_fmaf(hv, erfv, hv + negm);      // hv*(1+erfv) + negm
}

__device__ __forceinline__ void gl2lds16(const void* g, void* l) {
  __builtin_amdgcn_global_load_lds(
      (const __attribute__((address_space(1))) void*)g,
      (__attribute__((address_space(3))) void*)l, 16, 0, 0);
}

__device__ __forceinline__ unsigned pkrtz(float a, float b) {
  auto t = __builtin_amdgcn_cvt_pkrtz(a, b);   // __fp16 ext_vector(2)
  return __builtin_bit_cast(unsigned, t);
}

// ---------------------------------------------------------------------------
// Kernel 0: one-time W1,W2 f32 -> f16 (scratch in d_out head; attn overwrites).
// ---------------------------------------------------------------------------
__global__ __launch_bounds__(256) void wcvt_kernel(
    const float* __restrict__ W1, const float* __restrict__ W2,
    _Float16* __restrict__ Wh1, _Float16* __restrict__ Wh2)
{
  int i = blockIdx.x * 256 + threadIdx.x;
  Wh1[i] = (_Float16)W1[i];
  Wh2[i] = (_Float16)W2[i];
}

// ---------------------------------------------------------------------------
// Kernel 1: q/k projections (f16 MFMA, f32 accum, +bias) and x -> V^T (f16).
// ---------------------------------------------------------------------------
__global__ __launch_bounds__(256) void proj_tr_kernel(
    const float* __restrict__ x,
    const _Float16* __restrict__ Wh1, const float* __restrict__ b1,
    const _Float16* __restrict__ Wh2, const float* __restrict__ b2,
    _Float16* __restrict__ Qb, _Float16* __restrict__ Kb,
    _Float16* __restrict__ VT)
{
  const int tid  = threadIdx.x;
  const int wave = tid >> 6;
  const int lane = tid & 63;
  const int lhi  = lane >> 4;
  const int llo  = lane & 15;
  const int r0   = blockIdx.x * 64;
  const int wr0  = r0 + wave * 16;

  f16x8 a[4];
#pragma unroll
  for (int ks = 0; ks < 4; ++ks) {
    const float* p = x + (size_t)(wr0 + llo) * D_ + lhi * 8 + ks * 32;
    f16x8 t;
#pragma unroll
    for (int e = 0; e < 8; ++e) t[e] = (_Float16)p[e];
    a[ks] = t;
  }

  f32x4 accq[8], acck[8];
#pragma unroll
  for (int n = 0; n < 8; ++n) {
    accq[n] = (f32x4){0.f, 0.f, 0.f, 0.f};
    acck[n] = (f32x4){0.f, 0.f, 0.f, 0.f};
  }

#pragma unroll
  for (int n = 0; n < 8; ++n) {
    const int e = n * 16 + llo;
#pragma unroll
    for (int ks = 0; ks < 4; ++ks) {
      f16x8 w1f = *(const f16x8*)(Wh1 + (size_t)e * D_ + lhi * 8 + ks * 32);
      f16x8 w2f = *(const f16x8*)(Wh2 + (size_t)e * D_ + lhi * 8 + ks * 32);
      accq[n] = __builtin_amdgcn_mfma_f32_16x16x32_f16(a[ks], w1f, accq[n], 0, 0, 0);
      acck[n] = __builtin_amdgcn_mfma_f32_16x16x32_f16(a[ks], w2f, acck[n], 0, 0, 0);
    }
  }

#pragma unroll
  for (int n = 0; n < 8; ++n) {
    const int e = n * 16 + llo;
    const float bias1 = b1[e];
    const float bias2 = b2[e];
#pragma unroll
    for (int r = 0; r < 4; ++r) {
      const size_t row = (size_t)wr0 + lhi * 4 + r;
      Qb[row * D_ + e] = (_Float16)(accq[n][r] + bias1);
      Kb[row * D_ + e] = (_Float16)(acck[n][r] + bias2);
    }
  }

  const int bh = r0 / L_;
  const int l0 = r0 % L_;
  const int d  = tid & 127;
  const int rh = tid >> 7;
  _Float16* dst = VT + (size_t)bh * D_ * L_ + (size_t)d * L_ + l0 + rh * 32;
#pragma unroll
  for (int j = 0; j < 4; ++j) {
    f16x8 t;
#pragma unroll
    for (int e = 0; e < 8; ++e)
      t[e] = (_Float16)x[(size_t)(r0 + rh * 32 + j * 8 + e) * D_ + d];
    *(f16x8*)(dst + j * 8) = t;
  }
}

// ---------------------------------------------------------------------------
// Kernel 2: fused gelu(QK^T)->softmax->@V flash attention, 32x32x16 MFMA.
// R13 + CROSS-TILE QK PIPELINE: QK(t+1) issued at the top of body(t) into a
// second score set (K(t+1) already LDS-resident: barrier drains vmcnt every
// iter). Its MFMAs execute under softmax(t)'s VALU. K dbuf still suffices
// (buf[t&1] is dead in body(t)); one extra prologue barrier protects Ks[0].
// Manual 2x-unrolled loop = static register ping-pong (no dyn indexing).
// Bank conflicts: 0 (4-bit XOR swizzle + V [128][128] supertile, R13).
// ---------------------------------------------------------------------------
__global__ __launch_bounds__(512) void attn_kernel(
    const _Float16* __restrict__ Qb, const _Float16* __restrict__ Kb,
    const _Float16* __restrict__ VT, float* __restrict__ out)
{
  __shared__ _Float16 Ks[2][64 * 128];    // 2 x 16KB, K tile (64 k-rows)
  __shared__ _Float16 Vs[2][128 * 128];   // 2 x 32KB, V supertile (128 k)

  const int tid  = threadIdx.x;
  const int wave = tid >> 6;      // 0..7
  const int lane = tid & 63;
  const int l5   = lane & 31;
  const int hi   = lane >> 5;

  // XCD-aware swizzle: 512 blocks, 8 XCDs -> 8 whole heads per XCD.
  const int bid = blockIdx.x;
  const int blk = (bid & 7) * 64 + (bid >> 3);
  const int bh  = blk >> 3;            // 8 q-blocks (256 rows) per head
  const int q0  = (blk & 7) * 256;
  const int b   = bh >> 4;
  const int h   = bh & 15;
  const int wq0 = q0 + wave * 32;

  const char* KheadB = (const char*)(Kb + (size_t)bh * L_ * D_);
  const char* VheadB = (const char*)(VT + (size_t)bh * D_ * L_);

  // ---- staging constants ----
  int kdst[2], ksrc[2];
#pragma unroll
  for (int c = 0; c < 2; ++c) {
    const int wc = wave * 2 + c;
    kdst[c] = wc * 1024;                                // wave-uniform dest
    const int l  = wc * 4 + (lane >> 4);                // K-tile row
    const int c0 = (lane & 15) * 8;                     // col halves
    ksrc[c] = l * 256 + 2 * (c0 ^ ((l & 15) << 3));     // 4-bit pre-swizzle
  }
  int vdst[4], vsrc[4];
#pragma unroll
  for (int c = 0; c < 4; ++c) {
    vdst[c] = c * 8192 + wave * 1024;
    const int d  = c * 32 + wave * 4 + (lane >> 4);     // V row (d)
    const int c0 = (lane & 15) * 8;                     // col halves
    vsrc[c] = d * 4096 + 2 * (c0 ^ ((d & 15) << 3));    // 4-bit pre-swizzle
  }
  const int swz4 = (l5 & 15) << 3;                      // read-side XOR (halves)

  // Q fragments (B-operand of swapped QK^T): j = l5 = q-row, k = s*16+hi*8+e
  f16x8 qf[8];
#pragma unroll
  for (int s = 0; s < 8; ++s)
    qf[s] = *(const f16x8*)(Qb + ((size_t)bh * L_ + wq0 + l5) * D_ + s * 16 + hi * 8);

  f32x16 accO[4];
#pragma unroll
  for (int n = 0; n < 4; ++n)
#pragma unroll
    for (int r = 0; r < 16; ++r) accO[n][r] = 0.f;
  float negm = 64.f;   // -m in exp2 units; m init -64
  float l = 0.f;

  // ---- helpers ----
  auto stageK = [&](int tile) {        // tile index in [0,32)
    const char* kt_ = KheadB + (size_t)tile * 64 * 256;
    char* dst = (char*)&Ks[tile & 1][0];
#pragma unroll
    for (int c = 0; c < 2; ++c) gl2lds16(kt_ + ksrc[c], dst + kdst[c]);
  };
  auto stageV = [&](int sup) {         // supertile index in [0,16)
    const char* vt_ = VheadB + (size_t)sup * 256;
    char* dst = (char*)&Vs[sup & 1][0];
#pragma unroll
    for (int c = 0; c < 4; ++c) gl2lds16(vt_ + vsrc[c], dst + vdst[c]);
  };
  auto qk = [&](const _Float16* Kbuf, f32x16& dA, f32x16& dB) {
#pragma unroll
    for (int r = 0; r < 16; ++r) { dA[r] = 0.f; dB[r] = 0.f; }
    __builtin_amdgcn_s_setprio(1);
#pragma unroll
    for (int s = 0; s < 8; ++s) {
      f16x8 kfa = *(const f16x8*)(Kbuf + l5 * 128 + ((s * 16 + hi * 8) ^ swz4));
      dA = __builtin_amdgcn_mfma_f32_32x32x16_f16(kfa, qf[s], dA, 0, 0, 0);
      f16x8 kfb = *(const f16x8*)(Kbuf + (32 + l5) * 128 + ((s * 16 + hi * 8) ^ swz4));
      dB = __builtin_amdgcn_mfma_f32_32x32x16_f16(kfb, qf[s], dB, 0, 0, 0);
    }
    __builtin_amdgcn_s_setprio(0);
  };
  auto softmax_pv = [&](const f32x16& sT, const _Float16* Vcur, int vkbase) {
    float gm[16];
#pragma unroll
    for (int r = 0; r < 16; ++r) gm[r] = gelu_m(sT[r], negm);

    float tm = fmaxf(fmaxf(gm[0], gm[1]), gm[2]);
    tm = fmaxf(fmaxf(tm, gm[3]),  gm[4]);
    tm = fmaxf(fmaxf(tm, gm[5]),  gm[6]);
    tm = fmaxf(fmaxf(tm, gm[7]),  gm[8]);
    tm = fmaxf(fmaxf(tm, gm[9]),  gm[10]);
    tm = fmaxf(fmaxf(tm, gm[11]), gm[12]);
    tm = fmaxf(fmaxf(tm, gm[13]), gm[14]);
    tm = fmaxf(tm, gm[15]);
    tm = fmaxf(tm, __shfl_xor(tm, 32));

    float p[16];
    float ts;
    if (__all(tm <= 11.5415603f)) {
#pragma unroll
      for (int r = 0; r < 16; ++r) p[r] = __builtin_amdgcn_exp2f(gm[r]);
      float a0 = p[0]+p[1],   a1 = p[2]+p[3],   a2 = p[4]+p[5],   a3 = p[6]+p[7];
      float a4 = p[8]+p[9],   a5 = p[10]+p[11], a6 = p[12]+p[13], a7 = p[14]+p[15];
      ts = ((a0+a1)+(a2+a3)) + ((a4+a5)+(a6+a7));
      ts += __shfl_xor(ts, 32);
      l += ts;
    } else {
      float dm = fmaxf(tm, 0.f);
      negm -= dm;
      float sc = __builtin_amdgcn_exp2f(-dm);
#pragma unroll
      for (int r = 0; r < 16; ++r) p[r] = __builtin_amdgcn_exp2f(gm[r] - dm);
      float a0 = p[0]+p[1],   a1 = p[2]+p[3],   a2 = p[4]+p[5],   a3 = p[6]+p[7];
      float a4 = p[8]+p[9],   a5 = p[10]+p[11], a6 = p[12]+p[13], a7 = p[14]+p[15];
      ts = ((a0+a1)+(a2+a3)) + ((a4+a5)+(a6+a7));
      ts += __shfl_xor(ts, 32);
      l = __builtin_fmaf(l, sc, ts);
      float scr[16];
#pragma unroll
      for (int r = 0; r < 16; ++r)
        scr[r] = __shfl(sc, (r & 3) + 8 * (r >> 2) + 4 * hi);
#pragma unroll
      for (int n = 0; n < 4; ++n)
#pragma unroll
        for (int r = 0; r < 16; ++r) accO[n][r] *= scr[r];
    }

    // P -> PV A-fragments in-register (T12; distinct operands only)
    unsigned pk01 = pkrtz(p[0], p[1]),   pk23 = pkrtz(p[2], p[3]);
    unsigned pk45 = pkrtz(p[4], p[5]),   pk67 = pkrtz(p[6], p[7]);
    unsigned pk89 = pkrtz(p[8], p[9]),   pkAB = pkrtz(p[10], p[11]);
    unsigned pkCD = pkrtz(p[12], p[13]), pkEF = pkrtz(p[14], p[15]);
    u32x2 r0 = __builtin_amdgcn_permlane32_swap(pk01, pk45, false, false);
    u32x2 r1 = __builtin_amdgcn_permlane32_swap(pk23, pk67, false, false);
    u32x2 r2 = __builtin_amdgcn_permlane32_swap(pk89, pkCD, false, false);
    u32x2 r3 = __builtin_amdgcn_permlane32_swap(pkAB, pkEF, false, false);
    union { unsigned u[4]; f16x8 v; } A0c, A1c;
    A0c.u[0] = r0[0]; A0c.u[1] = r1[0]; A0c.u[2] = r0[1]; A0c.u[3] = r1[1];
    A1c.u[0] = r2[0]; A1c.u[1] = r3[0]; A1c.u[2] = r2[1]; A1c.u[3] = r3[1];

    __builtin_amdgcn_s_setprio(1);
#pragma unroll
    for (int n = 0; n < 4; ++n) {
      f16x8 vf0 = *(const f16x8*)(Vcur + (n * 32 + l5) * 128 +
                                  ((vkbase + hi * 8) ^ swz4));
      accO[n] = __builtin_amdgcn_mfma_f32_32x32x16_f16(A0c.v, vf0, accO[n], 0, 0, 0);
      f16x8 vf1 = *(const f16x8*)(Vcur + (n * 32 + l5) * 128 +
                                  ((vkbase + 16 + hi * 8) ^ swz4));
      accO[n] = __builtin_amdgcn_mfma_f32_32x32x16_f16(A1c.v, vf1, accO[n], 0, 0, 0);
    }
    __builtin_amdgcn_s_setprio(0);
  };

  // ---- prologue: K0, K1, V-super0 staged; QK(0) computed ----
  stageK(0);
  stageK(1);
  stageV(0);
  __syncthreads();                 // all staged (vmcnt drained by barrier)
  f32x16 sA, sB, s2A, s2B;
  qk(&Ks[0][0], sA, sB);           // scores for tile 0
  __syncthreads();                 // reads of Ks[0] done; body(0) may overwrite

  // ---- main loop, 2x unrolled for static score-register ping-pong ----
  for (int t = 0; t < 32; t += 2) {
    // body(t): consume sA/sB (tile t), produce s2A/s2B (tile t+1)
    if (t + 2 < 32) stageK(t + 2);
    if (((t >> 1) + 1) < 16) stageV((t >> 1) + 1);
    if (t + 1 < 32) qk(&Ks[(t + 1) & 1][0], s2A, s2B);
    {
      const _Float16* Vcur = &Vs[(t >> 1) & 1][0];
      const int vt0 = (t & 1) * 64;
      softmax_pv(sA, Vcur, vt0);
      softmax_pv(sB, Vcur, vt0 + 32);
    }
    __syncthreads();

    // body(t+1): consume s2A/s2B (tile t+1), produce sA/sB (tile t+2)
    const int u = t + 1;
    if (u + 2 < 32) stageK(u + 2);
    if (u + 1 < 32) qk(&Ks[(u + 1) & 1][0], sA, sB);
    {
      const _Float16* Vcur = &Vs[(u >> 1) & 1][0];
      const int vt0 = (u & 1) * 64;
      softmax_pv(s2A, Vcur, vt0);
      softmax_pv(s2B, Vcur, vt0 + 32);
    }
    __syncthreads();
  }

  // ---- epilogue: O[q][d] / l[q]; q = (r&3)+8*(r>>2)+4*hi, d = n*32+l5 ----
  float linv = __builtin_amdgcn_rcpf(l);
  float lb[16];
#pragma unroll
  for (int r = 0; r < 16; ++r)
    lb[r] = __shfl(linv, (r & 3) + 8 * (r >> 2) + 4 * hi);
#pragma unroll
  for (int n = 0; n < 4; ++n)
#pragma unroll
    for (int r = 0; r < 16; ++r) {
      const int i = wq0 + (r & 3) + 8 * (r >> 2) + 4 * hi;
      out[((size_t)(b * L_ + i) * H_ + h) * D_ + n * 32 + l5] = accO[n][r] * lb[r];
    }
}

extern "C" void kernel_launch(void* const* d_in, const int* in_sizes, int n_in,
                              void* d_out, int out_size, void* d_ws, size_t ws_size,
                              hipStream_t stream) {
  const float* x  = (const float*)d_in[0];
  const float* W1 = (const float*)d_in[1];
  const float* b1 = (const float*)d_in[2];
  const float* W2 = (const float*)d_in[3];
  const float* b2 = (const float*)d_in[4];
  float* out = (float*)d_out;

  const size_t N = (size_t)BH_ * L_ * D_;
  _Float16* Qb = (_Float16*)d_ws;
  _Float16* Kb = Qb + N;
  _Float16* VT = Kb + N;

  _Float16* Wh1 = (_Float16*)d_out;          // scratch; attn overwrites out
  _Float16* Wh2 = Wh1 + D_ * D_;

  wcvt_kernel<<<64, 256, 0, stream>>>(W1, W2, Wh1, Wh2);
  proj_tr_kernel<<<(BH_ * L_) / 64, 256, 0, stream>>>(x, Wh1, b1, Wh2, b2, Qb, Kb, VT);
  attn_kernel<<<BH_ * (L_ / 256), 512, 0, stream>>>(Qb, Kb, VT, out);
}

// Round 15
// 352.786 us; speedup vs baseline: 1.6979x; 1.6979x over previous
//
#include <hip/hip_runtime.h>
#include <hip/hip_bf16.h>

#define B_ 4
#define H_ 16
#define L_ 2048
#define D_ 128
#define BH_ 64

typedef __attribute__((ext_vector_type(8))) _Float16 f16x8;
typedef __attribute__((ext_vector_type(4))) float f32x4;
typedef __attribute__((ext_vector_type(16))) float f32x16;
typedef __attribute__((ext_vector_type(2))) unsigned u32x2;

#define L2E 1.44269504088896f

// gm = L2E*gelu(v) + negm, tanh-form GELU (|err vs exact-erf gelu| ~3e-4):
//   gelu(v) = 0.5 v (1 + tanh(0.7978845608 (v + 0.044715 v^3)))
//           = v * sigmoid(1.5957691 (v + 0.044715 v^3))
// In exp2 domain: 9 VALU ops (exp2 + rcp + 7) vs 13 for the rational erf.
// Tails are graceful: exp2(+inf)->den inf->rcp 0->gm=negm; exp2(0)->r=1.
__device__ __forceinline__ float gelu_m(float v, float negm) {
  float u  = v * v;
  float m1 = 0.044715f * u;
  float w  = __builtin_fmaf(m1, v, v);             // v + 0.044715 v^3
  float e  = __builtin_amdgcn_exp2f(-2.3020575f * w); // exp2(-2*0.79788*L2E*w)
  float r  = __builtin_amdgcn_rcpf(1.0f + e);      // sigmoid
  float t  = 1.44269504f * v;
  return __builtin_fmaf(t, r, negm);               // L2E*gelu(v) + negm
}

__device__ __forceinline__ void gl2lds16(const void* g, void* l) {
  __builtin_amdgcn_global_load_lds(
      (const __attribute__((address_space(1))) void*)g,
      (__attribute__((address_space(3))) void*)l, 16, 0, 0);
}

__device__ __forceinline__ unsigned pkrtz(float a, float b) {
  auto t = __builtin_amdgcn_cvt_pkrtz(a, b);   // __fp16 ext_vector(2)
  return __builtin_bit_cast(unsigned, t);
}

// ---------------------------------------------------------------------------
// Kernel 0: one-time W1,W2 f32 -> f16 (scratch in d_out head; attn overwrites).
// ---------------------------------------------------------------------------
__global__ __launch_bounds__(256) void wcvt_kernel(
    const float* __restrict__ W1, const float* __restrict__ W2,
    _Float16* __restrict__ Wh1, _Float16* __restrict__ Wh2)
{
  int i = blockIdx.x * 256 + threadIdx.x;
  Wh1[i] = (_Float16)W1[i];
  Wh2[i] = (_Float16)W2[i];
}

// ---------------------------------------------------------------------------
// Kernel 1: q/k projections (f16 MFMA, f32 accum, +bias) and x -> V^T (f16).
// ---------------------------------------------------------------------------
__global__ __launch_bounds__(256) void proj_tr_kernel(
    const float* __restrict__ x,
    const _Float16* __restrict__ Wh1, const float* __restrict__ b1,
    const _Float16* __restrict__ Wh2, const float* __restrict__ b2,
    _Float16* __restrict__ Qb, _Float16* __restrict__ Kb,
    _Float16* __restrict__ VT)
{
  const int tid  = threadIdx.x;
  const int wave = tid >> 6;
  const int lane = tid & 63;
  const int lhi  = lane >> 4;
  const int llo  = lane & 15;
  const int r0   = blockIdx.x * 64;
  const int wr0  = r0 + wave * 16;

  f16x8 a[4];
#pragma unroll
  for (int ks = 0; ks < 4; ++ks) {
    const float* p = x + (size_t)(wr0 + llo) * D_ + lhi * 8 + ks * 32;
    f16x8 t;
#pragma unroll
    for (int e = 0; e < 8; ++e) t[e] = (_Float16)p[e];
    a[ks] = t;
  }

  f32x4 accq[8], acck[8];
#pragma unroll
  for (int n = 0; n < 8; ++n) {
    accq[n] = (f32x4){0.f, 0.f, 0.f, 0.f};
    acck[n] = (f32x4){0.f, 0.f, 0.f, 0.f};
  }

#pragma unroll
  for (int n = 0; n < 8; ++n) {
    const int e = n * 16 + llo;
#pragma unroll
    for (int ks = 0; ks < 4; ++ks) {
      f16x8 w1f = *(const f16x8*)(Wh1 + (size_t)e * D_ + lhi * 8 + ks * 32);
      f16x8 w2f = *(const f16x8*)(Wh2 + (size_t)e * D_ + lhi * 8 + ks * 32);
      accq[n] = __builtin_amdgcn_mfma_f32_16x16x32_f16(a[ks], w1f, accq[n], 0, 0, 0);
      acck[n] = __builtin_amdgcn_mfma_f32_16x16x32_f16(a[ks], w2f, acck[n], 0, 0, 0);
    }
  }

#pragma unroll
  for (int n = 0; n < 8; ++n) {
    const int e = n * 16 + llo;
    const float bias1 = b1[e];
    const float bias2 = b2[e];
#pragma unroll
    for (int r = 0; r < 4; ++r) {
      const size_t row = (size_t)wr0 + lhi * 4 + r;
      Qb[row * D_ + e] = (_Float16)(accq[n][r] + bias1);
      Kb[row * D_ + e] = (_Float16)(acck[n][r] + bias2);
    }
  }

  const int bh = r0 / L_;
  const int l0 = r0 % L_;
  const int d  = tid & 127;
  const int rh = tid >> 7;
  _Float16* dst = VT + (size_t)bh * D_ * L_ + (size_t)d * L_ + l0 + rh * 32;
#pragma unroll
  for (int j = 0; j < 4; ++j) {
    f16x8 t;
#pragma unroll
    for (int e = 0; e < 8; ++e)
      t[e] = (_Float16)x[(size_t)(r0 + rh * 32 + j * 8 + e) * D_ + d];
    *(f16x8*)(dst + j * 8) = t;
  }
}

// ---------------------------------------------------------------------------
// Kernel 2: fused gelu(QK^T)->softmax->@V flash attention, 32x32x16 MFMA.
// R13 structure (best measured: 297us, bank conflicts 0): 8 waves x 32 q,
// K 64-row tiles + V [128][128] supertile in LDS, 4-bit XOR swizzle, dbuf,
// T15 within-tile pipeline, T12 in-reg P->A-frag, defer-max.
// R15 delta: tanh-form gelu (9 ops vs 13). R14 lesson: NO cross-tile score
// pipelining -- two extra f32x16 score sets spill (FETCH 49->134MB).
// ---------------------------------------------------------------------------
__global__ __launch_bounds__(512) void attn_kernel(
    const _Float16* __restrict__ Qb, const _Float16* __restrict__ Kb,
    const _Float16* __restrict__ VT, float* __restrict__ out)
{
  __shared__ _Float16 Ks[2][64 * 128];    // 2 x 16KB, K tile (64 k-rows)
  __shared__ _Float16 Vs[2][128 * 128];   // 2 x 32KB, V supertile (128 k)

  const int tid  = threadIdx.x;
  const int wave = tid >> 6;      // 0..7
  const int lane = tid & 63;
  const int l5   = lane & 31;
  const int hi   = lane >> 5;

  // XCD-aware swizzle: 512 blocks, 8 XCDs -> 8 whole heads per XCD.
  const int bid = blockIdx.x;
  const int blk = (bid & 7) * 64 + (bid >> 3);
  const int bh  = blk >> 3;            // 8 q-blocks (256 rows) per head
  const int q0  = (blk & 7) * 256;
  const int b   = bh >> 4;
  const int h   = bh & 15;
  const int wq0 = q0 + wave * 32;

  const char* KheadB = (const char*)(Kb + (size_t)bh * L_ * D_);
  const char* VheadB = (const char*)(VT + (size_t)bh * D_ * L_);

  // ---- staging constants ----
  int kdst[2], ksrc[2];
#pragma unroll
  for (int c = 0; c < 2; ++c) {
    const int wc = wave * 2 + c;
    kdst[c] = wc * 1024;                                // wave-uniform dest
    const int l  = wc * 4 + (lane >> 4);                // K-tile row
    const int c0 = (lane & 15) * 8;                     // col halves
    ksrc[c] = l * 256 + 2 * (c0 ^ ((l & 15) << 3));     // 4-bit pre-swizzle
  }
  int vdst[4], vsrc[4];
#pragma unroll
  for (int c = 0; c < 4; ++c) {
    vdst[c] = c * 8192 + wave * 1024;
    const int d  = c * 32 + wave * 4 + (lane >> 4);     // V row (d)
    const int c0 = (lane & 15) * 8;                     // col halves
    vsrc[c] = d * 4096 + 2 * (c0 ^ ((d & 15) << 3));    // 4-bit pre-swizzle
  }
  const int swz4 = (l5 & 15) << 3;                      // read-side XOR (halves)

  // Q fragments (B-operand of swapped QK^T): j = l5 = q-row, k = s*16+hi*8+e
  f16x8 qf[8];
#pragma unroll
  for (int s = 0; s < 8; ++s)
    qf[s] = *(const f16x8*)(Qb + ((size_t)bh * L_ + wq0 + l5) * D_ + s * 16 + hi * 8);

  f32x16 accO[4];
#pragma unroll
  for (int n = 0; n < 4; ++n)
#pragma unroll
    for (int r = 0; r < 16; ++r) accO[n][r] = 0.f;
  float negm = 64.f;   // -m in exp2 units; m init -64
  float l = 0.f;

  // ---- prologue: stage K tile 0 + V supertile 0 ----
#pragma unroll
  for (int c = 0; c < 2; ++c)
    gl2lds16(KheadB + ksrc[c], (char*)&Ks[0][0] + kdst[c]);
#pragma unroll
  for (int c = 0; c < 4; ++c)
    gl2lds16(VheadB + vsrc[c], (char*)&Vs[0][0] + vdst[c]);
  __syncthreads();

  for (int t = 0; t < L_ / 64; ++t) {
    const int kcur = t & 1;
    const int vcur = (t >> 1) & 1;
    // ---- prefetch: K every iter; V supertile every other iter ----
    if (t + 1 < L_ / 64) {
      const char* kt_ = KheadB + (size_t)(t + 1) * 64 * 256;
#pragma unroll
      for (int c = 0; c < 2; ++c)
        gl2lds16(kt_ + ksrc[c], (char*)&Ks[kcur ^ 1][0] + kdst[c]);
    }
    if ((t & 1) == 0 && (t >> 1) + 1 < L_ / 128) {
      const char* vt_ = VheadB + (size_t)((t >> 1) + 1) * 256;
#pragma unroll
      for (int c = 0; c < 4; ++c)
        gl2lds16(vt_ + vsrc[c], (char*)&Vs[vcur ^ 1][0] + vdst[c]);
    }
    const _Float16* Kcur = &Ks[kcur][0];
    const _Float16* Vcur = &Vs[vcur][0];
    const int vt0 = (t & 1) * 64;          // k-offset of this K-tile in V sup

    // ---- S^T for BOTH kb subtiles: two interleaved 8-deep chains ----
    f32x16 sA, sB;
#pragma unroll
    for (int r = 0; r < 16; ++r) { sA[r] = 0.f; sB[r] = 0.f; }
    __builtin_amdgcn_s_setprio(1);
#pragma unroll
    for (int s = 0; s < 8; ++s) {
      f16x8 kfa = *(const f16x8*)(Kcur + l5 * 128 +
                                  ((s * 16 + hi * 8) ^ swz4));
      sA = __builtin_amdgcn_mfma_f32_32x32x16_f16(kfa, qf[s], sA, 0, 0, 0);
      f16x8 kfb = *(const f16x8*)(Kcur + (32 + l5) * 128 +
                                  ((s * 16 + hi * 8) ^ swz4));
      sB = __builtin_amdgcn_mfma_f32_32x32x16_f16(kfb, qf[s], sB, 0, 0, 0);
    }
    __builtin_amdgcn_s_setprio(0);

    // ---- softmax + PV per subtile; PV(0) MFMA overlaps softmax(1) VALU ----
    auto softmax_pv = [&](const f32x16& sT, int vkbase) {
      float gm[16];
#pragma unroll
      for (int r = 0; r < 16; ++r) gm[r] = gelu_m(sT[r], negm);

      float tm = fmaxf(fmaxf(gm[0], gm[1]), gm[2]);
      tm = fmaxf(fmaxf(tm, gm[3]),  gm[4]);
      tm = fmaxf(fmaxf(tm, gm[5]),  gm[6]);
      tm = fmaxf(fmaxf(tm, gm[7]),  gm[8]);
      tm = fmaxf(fmaxf(tm, gm[9]),  gm[10]);
      tm = fmaxf(fmaxf(tm, gm[11]), gm[12]);
      tm = fmaxf(fmaxf(tm, gm[13]), gm[14]);
      tm = fmaxf(tm, gm[15]);
      tm = fmaxf(tm, __shfl_xor(tm, 32));

      float p[16];
      float ts;
      if (__all(tm <= 11.5415603f)) {
#pragma unroll
        for (int r = 0; r < 16; ++r) p[r] = __builtin_amdgcn_exp2f(gm[r]);
        float a0 = p[0]+p[1],   a1 = p[2]+p[3],   a2 = p[4]+p[5],   a3 = p[6]+p[7];
        float a4 = p[8]+p[9],   a5 = p[10]+p[11], a6 = p[12]+p[13], a7 = p[14]+p[15];
        ts = ((a0+a1)+(a2+a3)) + ((a4+a5)+(a6+a7));
        ts += __shfl_xor(ts, 32);
        l += ts;
      } else {
        float dm = fmaxf(tm, 0.f);
        negm -= dm;
        float sc = __builtin_amdgcn_exp2f(-dm);
#pragma unroll
        for (int r = 0; r < 16; ++r) p[r] = __builtin_amdgcn_exp2f(gm[r] - dm);
        float a0 = p[0]+p[1],   a1 = p[2]+p[3],   a2 = p[4]+p[5],   a3 = p[6]+p[7];
        float a4 = p[8]+p[9],   a5 = p[10]+p[11], a6 = p[12]+p[13], a7 = p[14]+p[15];
        ts = ((a0+a1)+(a2+a3)) + ((a4+a5)+(a6+a7));
        ts += __shfl_xor(ts, 32);
        l = __builtin_fmaf(l, sc, ts);
        float scr[16];
#pragma unroll
        for (int r = 0; r < 16; ++r)
          scr[r] = __shfl(sc, (r & 3) + 8 * (r >> 2) + 4 * hi);
#pragma unroll
        for (int n = 0; n < 4; ++n)
#pragma unroll
          for (int r = 0; r < 16; ++r) accO[n][r] *= scr[r];
      }

      // P -> PV A-fragments in-register (T12; distinct operands only)
      unsigned pk01 = pkrtz(p[0], p[1]),   pk23 = pkrtz(p[2], p[3]);
      unsigned pk45 = pkrtz(p[4], p[5]),   pk67 = pkrtz(p[6], p[7]);
      unsigned pk89 = pkrtz(p[8], p[9]),   pkAB = pkrtz(p[10], p[11]);
      unsigned pkCD = pkrtz(p[12], p[13]), pkEF = pkrtz(p[14], p[15]);
      u32x2 r0 = __builtin_amdgcn_permlane32_swap(pk01, pk45, false, false);
      u32x2 r1 = __builtin_amdgcn_permlane32_swap(pk23, pk67, false, false);
      u32x2 r2 = __builtin_amdgcn_permlane32_swap(pk89, pkCD, false, false);
      u32x2 r3 = __builtin_amdgcn_permlane32_swap(pkAB, pkEF, false, false);
      union { unsigned u[4]; f16x8 v; } A0c, A1c;
      A0c.u[0] = r0[0]; A0c.u[1] = r1[0]; A0c.u[2] = r0[1]; A0c.u[3] = r1[1];
      A1c.u[0] = r2[0]; A1c.u[1] = r3[0]; A1c.u[2] = r2[1]; A1c.u[3] = r3[1];

      // O += P @ V (V rows 128 halves in the supertile)
      __builtin_amdgcn_s_setprio(1);
#pragma unroll
      for (int n = 0; n < 4; ++n) {
        f16x8 vf0 = *(const f16x8*)(Vcur + (n * 32 + l5) * 128 +
                                    ((vkbase + hi * 8) ^ swz4));
        accO[n] = __builtin_amdgcn_mfma_f32_32x32x16_f16(A0c.v, vf0, accO[n], 0, 0, 0);
        f16x8 vf1 = *(const f16x8*)(Vcur + (n * 32 + l5) * 128 +
                                    ((vkbase + 16 + hi * 8) ^ swz4));
        accO[n] = __builtin_amdgcn_mfma_f32_32x32x16_f16(A1c.v, vf1, accO[n], 0, 0, 0);
      }
      __builtin_amdgcn_s_setprio(0);
    };

    softmax_pv(sA, vt0);
    softmax_pv(sB, vt0 + 32);

    __syncthreads();   // waves done with cur buffers; prefetches landed
  }

  // ---- epilogue: O[q][d] / l[q]; q = (r&3)+8*(r>>2)+4*hi, d = n*32+l5 ----
  float linv = __builtin_amdgcn_rcpf(l);
  float lb[16];
#pragma unroll
  for (int r = 0; r < 16; ++r)
    lb[r] = __shfl(linv, (r & 3) + 8 * (r >> 2) + 4 * hi);
#pragma unroll
  for (int n = 0; n < 4; ++n)
#pragma unroll
    for (int r = 0; r < 16; ++r) {
      const int i = wq0 + (r & 3) + 8 * (r >> 2) + 4 * hi;
      out[((size_t)(b * L_ + i) * H_ + h) * D_ + n * 32 + l5] = accO[n][r] * lb[r];
    }
}

extern "C" void kernel_launch(void* const* d_in, const int* in_sizes, int n_in,
                              void* d_out, int out_size, void* d_ws, size_t ws_size,
                              hipStream_t stream) {
  const float* x  = (const float*)d_in[0];
  const float* W1 = (const float*)d_in[1];
  const float* b1 = (const float*)d_in[2];
  const float* W2 = (const float*)d_in[3];
  const float* b2 = (const float*)d_in[4];
  float* out = (float*)d_out;

  const size_t N = (size_t)BH_ * L_ * D_;
  _Float16* Qb = (_Float16*)d_ws;
  _Float16* Kb = Qb + N;
  _Float16* VT = Kb + N;

  _Float16* Wh1 = (_Float16*)d_out;          // scratch; attn overwrites out
  _Float16* Wh2 = Wh1 + D_ * D_;

  wcvt_kernel<<<64, 256, 0, stream>>>(W1, W2, Wh1, Wh2);
  proj_tr_kernel<<<(BH_ * L_) / 64, 256, 0, stream>>>(x, Wh1, b1, Wh2, b2, Qb, Kb, VT);
  attn_kernel<<<BH_ * (L_ / 256), 512, 0, stream>>>(Qb, Kb, VT, out);
}

// Round 16
// 349.871 us; speedup vs baseline: 1.7121x; 1.0083x over previous
//
#include <hip/hip_runtime.h>
#include <hip/hip_bf16.h>

#define B_ 4
#define H_ 16
#define L_ 2048
#define D_ 128
#define BH_ 64

typedef __attribute__((ext_vector_type(8))) _Float16 f16x8;
typedef __attribute__((ext_vector_type(4))) float f32x4;
typedef __attribute__((ext_vector_type(16))) float f32x16;
typedef __attribute__((ext_vector_type(2))) unsigned u32x2;

#define L2E 1.44269504088896f

// gm = L2E*gelu(v) + negm, tanh-form GELU (|err vs exact-erf gelu| ~3e-4):
// 9 VALU ops; verified absmax-neutral in R15.
__device__ __forceinline__ float gelu_m(float v, float negm) {
  float u  = v * v;
  float m1 = 0.044715f * u;
  float w  = __builtin_fmaf(m1, v, v);             // v + 0.044715 v^3
  float e  = __builtin_amdgcn_exp2f(-2.3020575f * w); // exp2(-2*0.79788*L2E*w)
  float r  = __builtin_amdgcn_rcpf(1.0f + e);      // sigmoid
  float t  = 1.44269504f * v;
  return __builtin_fmaf(t, r, negm);               // L2E*gelu(v) + negm
}

__device__ __forceinline__ void gl2lds16(const void* g, void* l) {
  __builtin_amdgcn_global_load_lds(
      (const __attribute__((address_space(1))) void*)g,
      (__attribute__((address_space(3))) void*)l, 16, 0, 0);
}

__device__ __forceinline__ unsigned pkrtz(float a, float b) {
  auto t = __builtin_amdgcn_cvt_pkrtz(a, b);   // __fp16 ext_vector(2)
  return __builtin_bit_cast(unsigned, t);
}

// ---------------------------------------------------------------------------
// Kernel 0: one-time W1,W2 f32 -> f16 (scratch in d_out head; attn overwrites).
// ---------------------------------------------------------------------------
__global__ __launch_bounds__(256) void wcvt_kernel(
    const float* __restrict__ W1, const float* __restrict__ W2,
    _Float16* __restrict__ Wh1, _Float16* __restrict__ Wh2)
{
  int i = blockIdx.x * 256 + threadIdx.x;
  Wh1[i] = (_Float16)W1[i];
  Wh2[i] = (_Float16)W2[i];
}

// ---------------------------------------------------------------------------
// Kernel 1: q/k projections (f16 MFMA, f32 accum, +bias) and x -> V^T (f16).
// ---------------------------------------------------------------------------
__global__ __launch_bounds__(256) void proj_tr_kernel(
    const float* __restrict__ x,
    const _Float16* __restrict__ Wh1, const float* __restrict__ b1,
    const _Float16* __restrict__ Wh2, const float* __restrict__ b2,
    _Float16* __restrict__ Qb, _Float16* __restrict__ Kb,
    _Float16* __restrict__ VT)
{
  const int tid  = threadIdx.x;
  const int wave = tid >> 6;
  const int lane = tid & 63;
  const int lhi  = lane >> 4;
  const int llo  = lane & 15;
  const int r0   = blockIdx.x * 64;
  const int wr0  = r0 + wave * 16;

  f16x8 a[4];
#pragma unroll
  for (int ks = 0; ks < 4; ++ks) {
    const float* p = x + (size_t)(wr0 + llo) * D_ + lhi * 8 + ks * 32;
    f16x8 t;
#pragma unroll
    for (int e = 0; e < 8; ++e) t[e] = (_Float16)p[e];
    a[ks] = t;
  }

  f32x4 accq[8], acck[8];
#pragma unroll
  for (int n = 0; n < 8; ++n) {
    accq[n] = (f32x4){0.f, 0.f, 0.f, 0.f};
    acck[n] = (f32x4){0.f, 0.f, 0.f, 0.f};
  }

#pragma unroll
  for (int n = 0; n < 8; ++n) {
    const int e = n * 16 + llo;
#pragma unroll
    for (int ks = 0; ks < 4; ++ks) {
      f16x8 w1f = *(const f16x8*)(Wh1 + (size_t)e * D_ + lhi * 8 + ks * 32);
      f16x8 w2f = *(const f16x8*)(Wh2 + (size_t)e * D_ + lhi * 8 + ks * 32);
      accq[n] = __builtin_amdgcn_mfma_f32_16x16x32_f16(a[ks], w1f, accq[n], 0, 0, 0);
      acck[n] = __builtin_amdgcn_mfma_f32_16x16x32_f16(a[ks], w2f, acck[n], 0, 0, 0);
    }
  }

#pragma unroll
  for (int n = 0; n < 8; ++n) {
    const int e = n * 16 + llo;
    const float bias1 = b1[e];
    const float bias2 = b2[e];
#pragma unroll
    for (int r = 0; r < 4; ++r) {
      const size_t row = (size_t)wr0 + lhi * 4 + r;
      Qb[row * D_ + e] = (_Float16)(accq[n][r] + bias1);
      Kb[row * D_ + e] = (_Float16)(acck[n][r] + bias2);
    }
  }

  const int bh = r0 / L_;
  const int l0 = r0 % L_;
  const int d  = tid & 127;
  const int rh = tid >> 7;
  _Float16* dst = VT + (size_t)bh * D_ * L_ + (size_t)d * L_ + l0 + rh * 32;
#pragma unroll
  for (int j = 0; j < 4; ++j) {
    f16x8 t;
#pragma unroll
    for (int e = 0; e < 8; ++e)
      t[e] = (_Float16)x[(size_t)(r0 + rh * 32 + j * 8 + e) * D_ + d];
    *(f16x8*)(dst + j * 8) = t;
  }
}

// ---------------------------------------------------------------------------
// Kernel 2: fused gelu(QK^T)->softmax->@V flash attention, 32x32x16 MFMA.
// R15 + barrier halving: K staged as [128][128] supertile like V (LDS 128KB,
// free: we are reg-limited to 1 block/CU), 2 tiles (4 subtiles) per barrier
// -> 16 barriers instead of 32. l cross-half sum deferred to epilogue (negm
// stays synced via the tm max-shuffle; 64 DS-shuffles -> 1).
// R14 lesson: NO cross-tile score pipelining (extra f32x16 sets spill).
// ---------------------------------------------------------------------------
__global__ __launch_bounds__(512) void attn_kernel(
    const _Float16* __restrict__ Qb, const _Float16* __restrict__ Kb,
    const _Float16* __restrict__ VT, float* __restrict__ out)
{
  __shared__ _Float16 Ks[2][128 * 128];   // 2 x 32KB, K supertile (128 k-rows)
  __shared__ _Float16 Vs[2][128 * 128];   // 2 x 32KB, V supertile (128 k)

  const int tid  = threadIdx.x;
  const int wave = tid >> 6;      // 0..7
  const int lane = tid & 63;
  const int l5   = lane & 31;
  const int hi   = lane >> 5;

  // XCD-aware swizzle: 512 blocks, 8 XCDs -> 8 whole heads per XCD.
  const int bid = blockIdx.x;
  const int blk = (bid & 7) * 64 + (bid >> 3);
  const int bh  = blk >> 3;            // 8 q-blocks (256 rows) per head
  const int q0  = (blk & 7) * 256;
  const int b   = bh >> 4;
  const int h   = bh & 15;
  const int wq0 = q0 + wave * 32;

  const char* KheadB = (const char*)(Kb + (size_t)bh * L_ * D_);
  const char* VheadB = (const char*)(VT + (size_t)bh * D_ * L_);

  // ---- staging constants: K and V supertiles, 4 calls x 8KB each ----
  int sdst[4], ksrc[4], vsrc[4];
#pragma unroll
  for (int c = 0; c < 4; ++c) {
    const int row = c * 32 + wave * 4 + (lane >> 4);    // 0..127
    const int c0  = (lane & 15) * 8;                    // col halves
    sdst[c] = c * 8192 + wave * 1024;                   // wave-uniform dest
    ksrc[c] = row * 256  + 2 * (c0 ^ ((row & 15) << 3)); // K row = 256B
    vsrc[c] = row * 4096 + 2 * (c0 ^ ((row & 15) << 3)); // V row = L*2B
  }
  const int swz4 = (l5 & 15) << 3;                      // read-side XOR (halves)

  // Q fragments (B-operand of swapped QK^T): j = l5 = q-row, k = s*16+hi*8+e
  f16x8 qf[8];
#pragma unroll
  for (int s = 0; s < 8; ++s)
    qf[s] = *(const f16x8*)(Qb + ((size_t)bh * L_ + wq0 + l5) * D_ + s * 16 + hi * 8);

  f32x16 accO[4];
#pragma unroll
  for (int n = 0; n < 4; ++n)
#pragma unroll
    for (int r = 0; r < 16; ++r) accO[n][r] = 0.f;
  float negm = 64.f;   // -m in exp2 units; m init -64 (synced across hi pair)
  float l = 0.f;       // PER-HALF partial sum; combined once at epilogue

  // ---- prologue: stage K/V supertile 0 ----
#pragma unroll
  for (int c = 0; c < 4; ++c) {
    gl2lds16(KheadB + ksrc[c], (char*)&Ks[0][0] + sdst[c]);
    gl2lds16(VheadB + vsrc[c], (char*)&Vs[0][0] + sdst[c]);
  }
  __syncthreads();

  for (int ts = 0; ts < L_ / 128; ++ts) {   // 16 supertiles, 1 barrier each
    const int cur = ts & 1;
    // ---- prefetch next K/V supertile (in flight across 2 tile bodies) ----
    if (ts + 1 < L_ / 128) {
      const char* kt_ = KheadB + (size_t)(ts + 1) * 32768;
      const char* vt_ = VheadB + (size_t)(ts + 1) * 256;
#pragma unroll
      for (int c = 0; c < 4; ++c) {
        gl2lds16(kt_ + ksrc[c], (char*)&Ks[cur ^ 1][0] + sdst[c]);
        gl2lds16(vt_ + vsrc[c], (char*)&Vs[cur ^ 1][0] + sdst[c]);
      }
    }
    const _Float16* Vcur = &Vs[cur][0];

#pragma unroll
    for (int half = 0; half < 2; ++half) {   // two 64-k tiles per supertile
      const _Float16* Kcur = &Ks[cur][half * 64 * 128];
      const int vt0 = half * 64;             // k-offset in V supertile

      // ---- S^T for BOTH kb subtiles: two interleaved 8-deep chains ----
      f32x16 sA, sB;
#pragma unroll
      for (int r = 0; r < 16; ++r) { sA[r] = 0.f; sB[r] = 0.f; }
      __builtin_amdgcn_s_setprio(1);
#pragma unroll
      for (int s = 0; s < 8; ++s) {
        f16x8 kfa = *(const f16x8*)(Kcur + l5 * 128 +
                                    ((s * 16 + hi * 8) ^ swz4));
        sA = __builtin_amdgcn_mfma_f32_32x32x16_f16(kfa, qf[s], sA, 0, 0, 0);
        f16x8 kfb = *(const f16x8*)(Kcur + (32 + l5) * 128 +
                                    ((s * 16 + hi * 8) ^ swz4));
        sB = __builtin_amdgcn_mfma_f32_32x32x16_f16(kfb, qf[s], sB, 0, 0, 0);
      }
      __builtin_amdgcn_s_setprio(0);

      // ---- softmax + PV per subtile ----
      auto softmax_pv = [&](const f32x16& sT, int vkbase) {
        float gm[16];
#pragma unroll
        for (int r = 0; r < 16; ++r) gm[r] = gelu_m(sT[r], negm);

        float tm = fmaxf(fmaxf(gm[0], gm[1]), gm[2]);
        tm = fmaxf(fmaxf(tm, gm[3]),  gm[4]);
        tm = fmaxf(fmaxf(tm, gm[5]),  gm[6]);
        tm = fmaxf(fmaxf(tm, gm[7]),  gm[8]);
        tm = fmaxf(fmaxf(tm, gm[9]),  gm[10]);
        tm = fmaxf(fmaxf(tm, gm[11]), gm[12]);
        tm = fmaxf(fmaxf(tm, gm[13]), gm[14]);
        tm = fmaxf(tm, gm[15]);
        tm = fmaxf(tm, __shfl_xor(tm, 32));   // REQUIRED: negm shared by pair

        float p[16];
        float ts_;
        if (__all(tm <= 11.5415603f)) {
#pragma unroll
          for (int r = 0; r < 16; ++r) p[r] = __builtin_amdgcn_exp2f(gm[r]);
          float a0 = p[0]+p[1],   a1 = p[2]+p[3],   a2 = p[4]+p[5],   a3 = p[6]+p[7];
          float a4 = p[8]+p[9],   a5 = p[10]+p[11], a6 = p[12]+p[13], a7 = p[14]+p[15];
          ts_ = ((a0+a1)+(a2+a3)) + ((a4+a5)+(a6+a7));
          l += ts_;                            // per-half partial
        } else {
          float dm = fmaxf(tm, 0.f);
          negm -= dm;
          float sc = __builtin_amdgcn_exp2f(-dm);
#pragma unroll
          for (int r = 0; r < 16; ++r) p[r] = __builtin_amdgcn_exp2f(gm[r] - dm);
          float a0 = p[0]+p[1],   a1 = p[2]+p[3],   a2 = p[4]+p[5],   a3 = p[6]+p[7];
          float a4 = p[8]+p[9],   a5 = p[10]+p[11], a6 = p[12]+p[13], a7 = p[14]+p[15];
          ts_ = ((a0+a1)+(a2+a3)) + ((a4+a5)+(a6+a7));
          l = __builtin_fmaf(l, sc, ts_);      // sc uniform across pair
          float scr[16];
#pragma unroll
          for (int r = 0; r < 16; ++r)
            scr[r] = __shfl(sc, (r & 3) + 8 * (r >> 2) + 4 * hi);
#pragma unroll
          for (int n = 0; n < 4; ++n)
#pragma unroll
            for (int r = 0; r < 16; ++r) accO[n][r] *= scr[r];
        }

        // P -> PV A-fragments in-register (T12; distinct operands only)
        unsigned pk01 = pkrtz(p[0], p[1]),   pk23 = pkrtz(p[2], p[3]);
        unsigned pk45 = pkrtz(p[4], p[5]),   pk67 = pkrtz(p[6], p[7]);
        unsigned pk89 = pkrtz(p[8], p[9]),   pkAB = pkrtz(p[10], p[11]);
        unsigned pkCD = pkrtz(p[12], p[13]), pkEF = pkrtz(p[14], p[15]);
        u32x2 r0 = __builtin_amdgcn_permlane32_swap(pk01, pk45, false, false);
        u32x2 r1 = __builtin_amdgcn_permlane32_swap(pk23, pk67, false, false);
        u32x2 r2 = __builtin_amdgcn_permlane32_swap(pk89, pkCD, false, false);
        u32x2 r3 = __builtin_amdgcn_permlane32_swap(pkAB, pkEF, false, false);
        union { unsigned u[4]; f16x8 v; } A0c, A1c;
        A0c.u[0] = r0[0]; A0c.u[1] = r1[0]; A0c.u[2] = r0[1]; A0c.u[3] = r1[1];
        A1c.u[0] = r2[0]; A1c.u[1] = r3[0]; A1c.u[2] = r2[1]; A1c.u[3] = r3[1];

        // O += P @ V (V rows 128 halves in the supertile)
        __builtin_amdgcn_s_setprio(1);
#pragma unroll
        for (int n = 0; n < 4; ++n) {
          f16x8 vf0 = *(const f16x8*)(Vcur + (n * 32 + l5) * 128 +
                                      ((vkbase + hi * 8) ^ swz4));
          accO[n] = __builtin_amdgcn_mfma_f32_32x32x16_f16(A0c.v, vf0, accO[n], 0, 0, 0);
          f16x8 vf1 = *(const f16x8*)(Vcur + (n * 32 + l5) * 128 +
                                      ((vkbase + 16 + hi * 8) ^ swz4));
          accO[n] = __builtin_amdgcn_mfma_f32_32x32x16_f16(A1c.v, vf1, accO[n], 0, 0, 0);
        }
        __builtin_amdgcn_s_setprio(0);
      };

      softmax_pv(sA, vt0);
      softmax_pv(sB, vt0 + 32);
    }

    __syncthreads();   // one barrier per supertile (2 tiles); prefetch landed
  }

  // ---- epilogue: combine per-half l, then O[q][d] / l[q] ----
  l += __shfl_xor(l, 32);                    // the single cross-half l sum
  float linv = __builtin_amdgcn_rcpf(l);
  float lb[16];
#pragma unroll
  for (int r = 0; r < 16; ++r)
    lb[r] = __shfl(linv, (r & 3) + 8 * (r >> 2) + 4 * hi);
#pragma unroll
  for (int n = 0; n < 4; ++n)
#pragma unroll
    for (int r = 0; r < 16; ++r) {
      const int i = wq0 + (r & 3) + 8 * (r >> 2) + 4 * hi;
      out[((size_t)(b * L_ + i) * H_ + h) * D_ + n * 32 + l5] = accO[n][r] * lb[r];
    }
}

extern "C" void kernel_launch(void* const* d_in, const int* in_sizes, int n_in,
                              void* d_out, int out_size, void* d_ws, size_t ws_size,
                              hipStream_t stream) {
  const float* x  = (const float*)d_in[0];
  const float* W1 = (const float*)d_in[1];
  const float* b1 = (const float*)d_in[2];
  const float* W2 = (const float*)d_in[3];
  const float* b2 = (const float*)d_in[4];
  float* out = (float*)d_out;

  const size_t N = (size_t)BH_ * L_ * D_;
  _Float16* Qb = (_Float16*)d_ws;
  _Float16* Kb = Qb + N;
  _Float16* VT = Kb + N;

  _Float16* Wh1 = (_Float16*)d_out;          // scratch; attn overwrites out
  _Float16* Wh2 = Wh1 + D_ * D_;

  wcvt_kernel<<<64, 256, 0, stream>>>(W1, W2, Wh1, Wh2);
  proj_tr_kernel<<<(BH_ * L_) / 64, 256, 0, stream>>>(x, Wh1, b1, Wh2, b2, Qb, Kb, VT);
  attn_kernel<<<BH_ * (L_ / 256), 512, 0, stream>>>(Qb, Kb, VT, out);
}